// Round 8
// baseline (717.941 us; speedup 1.0000x reference)
//
#include <hip/hip_runtime.h>
#include <stdint.h>

typedef __bf16 bf16x8 __attribute__((ext_vector_type(8)));
typedef float f32x16 __attribute__((ext_vector_type(16)));

#define NN 4096
#define FF 64
#define BM 32
#define BK 64
#define NSTEP (NN / BK)  // 64
#define NKB (NN / 16)    // 256 k16-blocks

// round-to-nearest-even fp32 -> bf16
__device__ __forceinline__ unsigned short f2bf(float x) {
    unsigned int u = __builtin_bit_cast(unsigned int, x);
    unsigned int r = u + 0x7fffu + ((u >> 16) & 1u);
    return (unsigned short)(r >> 16);
}

__device__ __forceinline__ void gload16(const void* g, void* l) {
    __builtin_amdgcn_global_load_lds((const __attribute__((address_space(1))) void*)g,
                                     (__attribute__((address_space(3))) void*)l, 16, 0, 0);
}

// Pass 1: annP[b][kb][f][kh] = bf16(ann[b][kb*16+kh][f])  — B fragment for k-block kb
// is 16 B/lane, 1 KB contiguous per wave. (Validated R4/R6: absmax 0.5.)
__global__ __launch_bounds__(256) void annP_kernel(const float* __restrict__ ann,
                                                   unsigned short* __restrict__ annP) {
    int blk = blockIdx.x;
    int b = blk >> 6;
    int kb = (blk & 63) * 4 + (threadIdx.x >> 6);
    int f = threadIdx.x & 63;
    const float* src = ann + (size_t)(b * NN + kb * 16) * FF + f;
    unsigned short v[16];
#pragma unroll
    for (int kh = 0; kh < 16; ++kh) v[kh] = f2bf(src[(size_t)kh * FF]);
    unsigned int p[8];
#pragma unroll
    for (int i = 0; i < 8; ++i) p[i] = (unsigned)v[2 * i] | ((unsigned)v[2 * i + 1] << 16);
    uint4* dst = (uint4*)(annP + ((size_t)(b * NKB + kb) * 64 + f) * 16);
    dst[0] = make_uint4(p[0], p[1], p[2], p[3]);
    dst[1] = make_uint4(p[4], p[5], p[6], p[7]);
}

// Pass 2: depth-2+ pipeline, 4 LDS buffers. STAGE issued POST-barrier (fixes R7's
// cross-wave WAR race: stage target = buffer read at iter s-1, whose readers all
// passed this barrier). B fragments prefetched 1 iter ahead into named reg sets.
// FIFO: compiler's bfrag(s) wait (vmcnt<=12) before iter-s MFMAs transitively
// drains STAGE(s+1)/STAGE(s+2) well before their reads; explicit vmcnt(12) is a
// steady-state no-op that drains STAGE(0) in the prologue.
__global__ __launch_bounds__(128) void gconv_kernel(const float* __restrict__ A,
                                                    const unsigned short* __restrict__ annP,
                                                    const float* __restrict__ bias,
                                                    float* __restrict__ out) {
    __shared__ alignas(16) char lds[4][8192];  // 32 rows x 64 k fp32, quad-buffered

    int bi = blockIdx.x;
    int b = bi & 7;            // batch == XCD -> annP[b] (512 KB) L2-resident per XCD
    int n0 = (bi >> 3) << 5;   // 128 row-tiles per batch
    int t = threadIdx.x, lane = t & 63, wf = t >> 6;  // 2 waves: f-halves
    int r = lane & 31, h = lane >> 5;

    const float* Ab = A + (size_t)b * NN * NN + (size_t)n0 * NN;

    // staging sources: LDS slot byte p = j*2048 + t*16 holds A[row][k0 + q*4 .. +3]
    // row = p>>8 (256 B rows), q = ((p&255) ^ ((row&15)<<4)) >> 4
    const float* asrc[4];
#pragma unroll
    for (int j = 0; j < 4; ++j) {
        unsigned p = (unsigned)(j * 2048 + t * 16);
        unsigned row = p >> 8;
        unsigned q = ((p & 255u) ^ ((row & 15u) << 4)) >> 4;
        asrc[j] = Ab + (size_t)row * NN + q * 4;
    }
    auto STAGE = [&](int buf, int k0) {
        char* base = lds[buf];
#pragma unroll
        for (int j = 0; j < 4; ++j) gload16(asrc[j] + k0, base + j * 2048 + wf * 1024);
    };

    // B fragment base: lane -> (f = wf*32 + r, k-half h); fragment kb at +kb*1024 elems
    const unsigned short* bfp =
        annP + (size_t)b * NKB * 1024 + (size_t)(wf * 32 + r) * 16 + h * 8;

    unsigned rbase = (unsigned)(r * 256);
    unsigned swz = (unsigned)((r & 15) << 4);

    f32x16 acc = {};
    uint4 bfA[4], bfB[4];  // named B-fragment double buffer (static indexing)

    auto loadB = [&](uint4 (&bf)[4], int s) {
        int kb0 = s * 4;
#pragma unroll
        for (int kc = 0; kc < 4; ++kc)
            bf[kc] = *(const uint4*)(bfp + (size_t)(kb0 + kc) * 1024);
    };
    auto compute = [&](const uint4 (&bf)[4], int s) {
        const char* bufA = lds[s & 3];
#pragma unroll
        for (int kc = 0; kc < 4; ++kc) {
            unsigned ao = rbase + (unsigned)(kc * 64 + h * 32);
            float4 a0 = *(const float4*)(bufA + (ao ^ swz));
            float4 a1 = *(const float4*)(bufA + ((ao + 16) ^ swz));
            bf16x8 af = {(__bf16)a0.x, (__bf16)a0.y, (__bf16)a0.z, (__bf16)a0.w,
                         (__bf16)a1.x, (__bf16)a1.y, (__bf16)a1.z, (__bf16)a1.w};
            acc = __builtin_amdgcn_mfma_f32_32x32x16_bf16(
                af, __builtin_bit_cast(bf16x8, bf[kc]), acc, 0, 0, 0);
        }
    };

    STAGE(0, 0);
    STAGE(1, BK);
    STAGE(2, 2 * BK);
    loadB(bfA, 0);

#pragma unroll 1
    for (int i = 0; i < NSTEP / 2; ++i) {
        int s0 = 2 * i;
        // ---- body A (step s0, consumes bfA) ----
        asm volatile("s_waitcnt vmcnt(12)" ::: "memory");
        __builtin_amdgcn_s_barrier();
        asm volatile("" ::: "memory");
        if (s0 + 1 < NSTEP) loadB(bfB, s0 + 1);          // B before STAGE (FIFO order)
        if (s0 + 3 < NSTEP) STAGE((s0 + 3) & 3, (s0 + 3) * BK);
        compute(bfA, s0);
        // ---- body B (step s0+1, consumes bfB) ----
        int s1 = s0 + 1;
        asm volatile("s_waitcnt vmcnt(12)" ::: "memory");
        __builtin_amdgcn_s_barrier();
        asm volatile("" ::: "memory");
        if (s1 + 1 < NSTEP) loadB(bfA, s1 + 1);
        if (s1 + 3 < NSTEP) STAGE((s1 + 3) & 3, (s1 + 3) * BK);
        compute(bfB, s1);
    }

    // epilogue: D col = lane&31 (f), row = (reg&3) + 8*(reg>>2) + 4*(lane>>5)  (verified)
    float bv = bias[wf * 32 + r];
    float* ob = out + ((size_t)(b * NN + n0)) * FF + wf * 32 + r;
#pragma unroll
    for (int e = 0; e < 16; ++e) {
        int rowl = (e & 3) + 8 * (e >> 2) + h * 4;
        ob[(size_t)rowl * FF] = acc[e] + bv;
    }
}

extern "C" void kernel_launch(void* const* d_in, const int* in_sizes, int n_in,
                              void* d_out, int out_size, void* d_ws, size_t ws_size,
                              hipStream_t stream) {
    const float* adj = (const float*)d_in[0];
    const float* ann = (const float*)d_in[1];
    const float* bias = (const float*)d_in[2];
    float* out = (float*)d_out;
    unsigned short* annP = (unsigned short*)d_ws;  // 8*256*64*16*2 = 4 MiB

    annP_kernel<<<dim3(8 * 64), dim3(256), 0, stream>>>(ann, annP);
    gconv_kernel<<<dim3(8 * (NN / BM)), dim3(128), 0, stream>>>(adj, annP, bias, out);
}